// Round 5
// baseline (152.296 us; speedup 1.0000x reference)
//
#include <hip/hip_runtime.h>
#include <math.h>

constexpr int NROWS = 524288;
constexpr float PI_F = 3.14159265358979323846f;
constexpr int BLOCK = 256;
constexpr int PA_BLOCKS = 512;                       // pose/trans + small latent share
constexpr int TOTAL_BLOCKS = 2048;
constexpr int CA = 2560;                             // latent float4 per PA block (10/thread)
constexpr int CB = 4608;                             // latent float4 per PB block (18/thread)
// exact: 512*2560 + 1536*4608 == 8388608 == NROWS*64/4

// d_ws layout: part[3*TOTAL_BLOCKS] floats (rot, trans, latent partials),
//              then u32 counter at byte offset 3*TOTAL_BLOCKS*4.
// kernel_launch zeroes only the counter (4 B) with hipMemsetAsync.

__device__ __forceinline__ void rot_mat(float r0, float r1, float r2, float R[9]) {
    // R = Rz2(-r2) * Rx(pi/2 + r1) * Rz(-r0), closed form
    float sa, ca, se, ce, st, ct;
    __sincosf(-r0, &sa, &ca);
    __sincosf(1.57079632679489662f + r1, &se, &ce);
    __sincosf(-r2, &st, &ct);
    R[0] =  ct * ca - st * ce * sa;
    R[1] = -ct * sa - st * ce * ca;
    R[2] =  st * se;
    R[3] =  st * ca + ct * ce * sa;
    R[4] = -st * sa + ct * ce * ca;
    R[5] = -ct * se;
    R[6] =  se * sa;
    R[7] =  se * ca;
    R[8] =  ce;
}

__device__ __forceinline__ void quat(float x0, float x1, float x2, float q[4]) {
    float sr, cr, sp, cp, sy, cy;
    __sincosf(x0 * 0.5f, &sr, &cr);
    __sincosf(x1 * 0.5f, &sp, &cp);
    __sincosf(x2 * 0.5f, &sy, &cy);
    q[0] = sr * cp * cy - cr * sp * sy;
    q[1] = cr * sp * cy + sr * cp * sy;
    q[2] = cr * cp * sy - sr * sp * cy;
    q[3] = cr * cp * cy + sr * sp * sy;
}

__device__ __forceinline__ void latent_chunk(
    const float4* __restrict__ lp, const float4* __restrict__ lg,
    int start, int count_per_thread, int tix, float& s2)
{
    int i = start + tix;
    // 2-deep MLP unroll; count_per_thread is even (10 or 18)
    for (int j = 0; j < count_per_thread; j += 2, i += 2 * BLOCK) {
        float4 p0 = lp[i],         g0 = lg[i];
        float4 p1 = lp[i + BLOCK], g1 = lg[i + BLOCK];
        float e;
        e = p0.x - g0.x; s2 += e * e;
        e = p0.y - g0.y; s2 += e * e;
        e = p0.z - g0.z; s2 += e * e;
        e = p0.w - g0.w; s2 += e * e;
        e = p1.x - g1.x; s2 += e * e;
        e = p1.y - g1.y; s2 += e * e;
        e = p1.z - g1.z; s2 += e * e;
        e = p1.w - g1.w; s2 += e * e;
    }
}

__global__ __launch_bounds__(256) void crit_fused_kernel(
    const float* __restrict__ pose_pred, const float* __restrict__ pose_gt,
    const float* __restrict__ trans_pred, const float* __restrict__ trans_gt,
    const float* __restrict__ latent_pred, const float* __restrict__ latent_gt,
    float* __restrict__ out, float* __restrict__ part, unsigned int* __restrict__ cnt)
{
    float s0 = 0.0f, s1 = 0.0f, s2 = 0.0f;   // rot_sq, trans_sq, latent_sq partials
    const int b = blockIdx.x;
    const int tix = threadIdx.x;
    const float4* __restrict__ lp = reinterpret_cast<const float4*>(latent_pred);
    const float4* __restrict__ lg = reinterpret_cast<const float4*>(latent_gt);

    if (b < PA_BLOCKS) {
        // ---------- pose + trans phase: 4 rows per thread, float4 loads ----------
        const int t = b * BLOCK + tix;                    // [0, 131072)
        {
            const float4* pp4 = reinterpret_cast<const float4*>(pose_pred);
            const float4* pg4 = reinterpret_cast<const float4*>(pose_gt);
            float4 A0 = pp4[3*t+0], A1 = pp4[3*t+1], A2 = pp4[3*t+2];
            float4 B0 = pg4[3*t+0], B1 = pg4[3*t+1], B2 = pg4[3*t+2];
            float pp[12] = {A0.x,A0.y,A0.z,A0.w, A1.x,A1.y,A1.z,A1.w, A2.x,A2.y,A2.z,A2.w};
            float pg[12] = {B0.x,B0.y,B0.z,B0.w, B1.x,B1.y,B1.z,B1.w, B2.x,B2.y,B2.z,B2.w};
            #pragma unroll
            for (int r = 0; r < 4; ++r) {
                float x0 = pp[3*r]*PI_F, x1 = pp[3*r+1]*PI_F, x2 = pp[3*r+2]*PI_F;
                float y0 = pg[3*r]*PI_F, y1 = pg[3*r+1]*PI_F, y2 = pg[3*r+2]*PI_F;
                float qp[4], qg[4];
                quat(x0, x1, x2, qp);
                quat(y0, y1, y2, qg);
                #pragma unroll
                for (int k = 0; k < 4; ++k) { float d = qp[k] - qg[k]; s0 += d * d; }
                float Rp[9], Rg[9];
                rot_mat(x0, x1, x2, Rp);
                rot_mat(y0, y1, y2, Rg);
                float tr = 0.0f;
                #pragma unroll
                for (int k = 0; k < 9; ++k) tr += Rp[k] * Rg[k];
                float c = fminf(1.0f, fmaxf(-1.0f, (tr - 1.0f) * 0.5f));
                out[3 + 4*t + r] = acosf(c) * (180.0f / PI_F);
            }
        }
        {
            const float4* tp4 = reinterpret_cast<const float4*>(trans_pred);
            const float4* tg4 = reinterpret_cast<const float4*>(trans_gt);
            float4 C0 = tp4[3*t+0], C1 = tp4[3*t+1], C2 = tp4[3*t+2];
            float4 D0 = tg4[3*t+0], D1 = tg4[3*t+1], D2 = tg4[3*t+2];
            float tp[12] = {C0.x,C0.y,C0.z,C0.w, C1.x,C1.y,C1.z,C1.w, C2.x,C2.y,C2.z,C2.w};
            float tg[12] = {D0.x,D0.y,D0.z,D0.w, D1.x,D1.y,D1.z,D1.w, D2.x,D2.y,D2.z,D2.w};
            #pragma unroll
            for (int r = 0; r < 4; ++r) {
                float p0 = tp[3*r], p1 = tp[3*r+1], p2 = tp[3*r+2];
                float g0 = tg[3*r], g1 = tg[3*r+1], g2 = tg[3*r+2];
                float d0 = p0-g0, d1 = p1-g1, d2 = p2-g2;
                s1 += d0*d0 + d1*d1 + d2*d2;
                float a1 = g0*g1 - p0*p1;
                float a2 = g0*g2 - p0*p2;
                out[3 + NROWS + 4*t + r] = sqrtf(a1*a1 + a2*a2) * 100.0f;
            }
        }
        latent_chunk(lp, lg, b * CA, CA / BLOCK, tix, s2);
    } else {
        const int start = PA_BLOCKS * CA + (b - PA_BLOCKS) * CB;
        latent_chunk(lp, lg, start, CB / BLOCK, tix, s2);
    }

    // ---------- block reduction: wave shuffle then LDS across 4 waves ----------
    #pragma unroll
    for (int off = 32; off > 0; off >>= 1) {
        s0 += __shfl_down(s0, off, 64);
        s1 += __shfl_down(s1, off, 64);
        s2 += __shfl_down(s2, off, 64);
    }
    __shared__ float sp[3][4];
    __shared__ bool is_last;
    const int lane = threadIdx.x & 63;
    const int wave = threadIdx.x >> 6;
    if (lane == 0) { sp[0][wave] = s0; sp[1][wave] = s1; sp[2][wave] = s2; }
    __syncthreads();

    if (tix == 0) {
        part[0*TOTAL_BLOCKS + b] = sp[0][0] + sp[0][1] + sp[0][2] + sp[0][3];
        part[1*TOTAL_BLOCKS + b] = sp[1][0] + sp[1][1] + sp[1][2] + sp[1][3];
        part[2*TOTAL_BLOCKS + b] = sp[2][0] + sp[2][1] + sp[2][2] + sp[2][3];
        __threadfence();                       // release: partials visible device-wide
        unsigned int old = atomicAdd(cnt, 1u); // native u32 atomic, one per block
        is_last = (old == TOTAL_BLOCKS - 1);
    }
    __syncthreads();

    if (is_last) {
        __threadfence();                       // acquire: see all partials
        double a0 = 0.0, a1 = 0.0, a2 = 0.0;
        for (int j = tix; j < TOTAL_BLOCKS; j += BLOCK) {
            a0 += (double)part[0*TOTAL_BLOCKS + j];
            a1 += (double)part[1*TOTAL_BLOCKS + j];
            a2 += (double)part[2*TOTAL_BLOCKS + j];
        }
        #pragma unroll
        for (int off = 32; off > 0; off >>= 1) {
            a0 += __shfl_down(a0, off, 64);
            a1 += __shfl_down(a1, off, 64);
            a2 += __shfl_down(a2, off, 64);
        }
        __shared__ double dp[3][4];
        if (lane == 0) { dp[0][wave] = a0; dp[1][wave] = a1; dp[2][wave] = a2; }
        __syncthreads();
        if (tix == 0) {
            double r = dp[0][0] + dp[0][1] + dp[0][2] + dp[0][3];
            double t = dp[1][0] + dp[1][1] + dp[1][2] + dp[1][3];
            double l = dp[2][0] + dp[2][1] + dp[2][2] + dp[2][3];
            out[0] = (float)(r / (4.0  * NROWS));
            out[1] = (float)(t / (3.0  * NROWS));
            out[2] = (float)(l / (64.0 * NROWS));
        }
    }
}

extern "C" void kernel_launch(void* const* d_in, const int* in_sizes, int n_in,
                              void* d_out, int out_size, void* d_ws, size_t ws_size,
                              hipStream_t stream) {
    const float* pose_pred   = (const float*)d_in[0];
    const float* pose_gt     = (const float*)d_in[1];
    const float* trans_pred  = (const float*)d_in[2];
    const float* trans_gt    = (const float*)d_in[3];
    const float* latent_pred = (const float*)d_in[4];
    const float* latent_gt   = (const float*)d_in[5];
    float* out  = (float*)d_out;
    float* part = (float*)d_ws;                                         // 3*2048 floats
    unsigned int* cnt = (unsigned int*)((char*)d_ws + 3 * TOTAL_BLOCKS * 4);

    hipMemsetAsync(cnt, 0, 4, stream);     // zero counter only (capture-safe)
    hipLaunchKernelGGL(crit_fused_kernel, dim3(TOTAL_BLOCKS), dim3(BLOCK), 0, stream,
                       pose_pred, pose_gt, trans_pred, trans_gt,
                       latent_pred, latent_gt, out, part, cnt);
}

// Round 6
// 49.934 us; speedup vs baseline: 3.0499x; 3.0499x over previous
//
#include <hip/hip_runtime.h>
#include <math.h>

constexpr int NROWS = 524288;
constexpr float PI_F = 3.14159265358979323846f;
constexpr int BLOCK = 256;
constexpr int PA_BLOCKS = 512;                       // pose/trans + small latent share
constexpr int TOTAL_BLOCKS = 2048;
constexpr int CA = 2560;                             // latent float4 per PA block (10/thread)
constexpr int CB = 4608;                             // latent float4 per PB block (18/thread)
// exact: 512*2560 + 1536*4608 == 8388608 == NROWS*64/4

// d_ws layout (floats): part[0*T+b]=rot, part[1*T+b]=trans, part[2*T+b]=latent
// (T = TOTAL_BLOCKS; each section is 2048 floats = 512 float4, 16B-aligned)

__device__ __forceinline__ void rot_mat(float r0, float r1, float r2, float R[9]) {
    // R = Rz2(-r2) * Rx(pi/2 + r1) * Rz(-r0), closed form
    float sa, ca, se, ce, st, ct;
    __sincosf(-r0, &sa, &ca);
    __sincosf(1.57079632679489662f + r1, &se, &ce);
    __sincosf(-r2, &st, &ct);
    R[0] =  ct * ca - st * ce * sa;
    R[1] = -ct * sa - st * ce * ca;
    R[2] =  st * se;
    R[3] =  st * ca + ct * ce * sa;
    R[4] = -st * sa + ct * ce * ca;
    R[5] = -ct * se;
    R[6] =  se * sa;
    R[7] =  se * ca;
    R[8] =  ce;
}

__device__ __forceinline__ void quat(float x0, float x1, float x2, float q[4]) {
    float sr, cr, sp, cp, sy, cy;
    __sincosf(x0 * 0.5f, &sr, &cr);
    __sincosf(x1 * 0.5f, &sp, &cp);
    __sincosf(x2 * 0.5f, &sy, &cy);
    q[0] = sr * cp * cy - cr * sp * sy;
    q[1] = cr * sp * cy + sr * cp * sy;
    q[2] = cr * cp * sy - sr * sp * cy;
    q[3] = cr * cp * cy + sr * sp * sy;
}

__device__ __forceinline__ void latent_chunk(
    const float4* __restrict__ lp, const float4* __restrict__ lg,
    int start, int count_per_thread, int tix, float& s2)
{
    int i = start + tix;
    // 2-deep MLP unroll; count_per_thread is even (10 or 18)
    for (int j = 0; j < count_per_thread; j += 2, i += 2 * BLOCK) {
        float4 p0 = lp[i],         g0 = lg[i];
        float4 p1 = lp[i + BLOCK], g1 = lg[i + BLOCK];
        float e;
        e = p0.x - g0.x; s2 += e * e;
        e = p0.y - g0.y; s2 += e * e;
        e = p0.z - g0.z; s2 += e * e;
        e = p0.w - g0.w; s2 += e * e;
        e = p1.x - g1.x; s2 += e * e;
        e = p1.y - g1.y; s2 += e * e;
        e = p1.z - g1.z; s2 += e * e;
        e = p1.w - g1.w; s2 += e * e;
    }
}

__global__ __launch_bounds__(256) void crit_fused_kernel(
    const float* __restrict__ pose_pred, const float* __restrict__ pose_gt,
    const float* __restrict__ trans_pred, const float* __restrict__ trans_gt,
    const float* __restrict__ latent_pred, const float* __restrict__ latent_gt,
    float* __restrict__ out, float* __restrict__ part)
{
    float s0 = 0.0f, s1 = 0.0f, s2 = 0.0f;   // rot_sq, trans_sq, latent_sq partials
    const int b = blockIdx.x;
    const int tix = threadIdx.x;
    const float4* __restrict__ lp = reinterpret_cast<const float4*>(latent_pred);
    const float4* __restrict__ lg = reinterpret_cast<const float4*>(latent_gt);

    if (b < PA_BLOCKS) {
        // ---------- pose + trans phase: 4 rows per thread, float4 loads ----------
        const int t = b * BLOCK + tix;                    // [0, 131072)
        {
            const float4* pp4 = reinterpret_cast<const float4*>(pose_pred);
            const float4* pg4 = reinterpret_cast<const float4*>(pose_gt);
            float4 A0 = pp4[3*t+0], A1 = pp4[3*t+1], A2 = pp4[3*t+2];
            float4 B0 = pg4[3*t+0], B1 = pg4[3*t+1], B2 = pg4[3*t+2];
            float pp[12] = {A0.x,A0.y,A0.z,A0.w, A1.x,A1.y,A1.z,A1.w, A2.x,A2.y,A2.z,A2.w};
            float pg[12] = {B0.x,B0.y,B0.z,B0.w, B1.x,B1.y,B1.z,B1.w, B2.x,B2.y,B2.z,B2.w};
            #pragma unroll
            for (int r = 0; r < 4; ++r) {
                float x0 = pp[3*r]*PI_F, x1 = pp[3*r+1]*PI_F, x2 = pp[3*r+2]*PI_F;
                float y0 = pg[3*r]*PI_F, y1 = pg[3*r+1]*PI_F, y2 = pg[3*r+2]*PI_F;
                float qp[4], qg[4];
                quat(x0, x1, x2, qp);
                quat(y0, y1, y2, qg);
                #pragma unroll
                for (int k = 0; k < 4; ++k) { float d = qp[k] - qg[k]; s0 += d * d; }
                float Rp[9], Rg[9];
                rot_mat(x0, x1, x2, Rp);
                rot_mat(y0, y1, y2, Rg);
                float tr = 0.0f;
                #pragma unroll
                for (int k = 0; k < 9; ++k) tr += Rp[k] * Rg[k];
                float c = fminf(1.0f, fmaxf(-1.0f, (tr - 1.0f) * 0.5f));
                out[3 + 4*t + r] = acosf(c) * (180.0f / PI_F);
            }
        }
        {
            const float4* tp4 = reinterpret_cast<const float4*>(trans_pred);
            const float4* tg4 = reinterpret_cast<const float4*>(trans_gt);
            float4 C0 = tp4[3*t+0], C1 = tp4[3*t+1], C2 = tp4[3*t+2];
            float4 D0 = tg4[3*t+0], D1 = tg4[3*t+1], D2 = tg4[3*t+2];
            float tp[12] = {C0.x,C0.y,C0.z,C0.w, C1.x,C1.y,C1.z,C1.w, C2.x,C2.y,C2.z,C2.w};
            float tg[12] = {D0.x,D0.y,D0.z,D0.w, D1.x,D1.y,D1.z,D1.w, D2.x,D2.y,D2.z,D2.w};
            #pragma unroll
            for (int r = 0; r < 4; ++r) {
                float p0 = tp[3*r], p1 = tp[3*r+1], p2 = tp[3*r+2];
                float g0 = tg[3*r], g1 = tg[3*r+1], g2 = tg[3*r+2];
                float d0 = p0-g0, d1 = p1-g1, d2 = p2-g2;
                s1 += d0*d0 + d1*d1 + d2*d2;
                float a1 = g0*g1 - p0*p1;
                float a2 = g0*g2 - p0*p2;
                out[3 + NROWS + 4*t + r] = sqrtf(a1*a1 + a2*a2) * 100.0f;
            }
        }
        latent_chunk(lp, lg, b * CA, CA / BLOCK, tix, s2);
    } else {
        const int start = PA_BLOCKS * CA + (b - PA_BLOCKS) * CB;
        latent_chunk(lp, lg, start, CB / BLOCK, tix, s2);
    }

    // ---------- block reduction: wave shuffle then LDS across 4 waves ----------
    #pragma unroll
    for (int off = 32; off > 0; off >>= 1) {
        s0 += __shfl_down(s0, off, 64);
        s1 += __shfl_down(s1, off, 64);
        s2 += __shfl_down(s2, off, 64);
    }
    __shared__ float sp[3][4];
    const int lane = threadIdx.x & 63;
    const int wave = threadIdx.x >> 6;
    if (lane == 0) { sp[0][wave] = s0; sp[1][wave] = s1; sp[2][wave] = s2; }
    __syncthreads();
    if (tix == 0) {
        part[0*TOTAL_BLOCKS + b] = sp[0][0] + sp[0][1] + sp[0][2] + sp[0][3];
        part[1*TOTAL_BLOCKS + b] = sp[1][0] + sp[1][1] + sp[1][2] + sp[1][3];
        part[2*TOTAL_BLOCKS + b] = sp[2][0] + sp[2][1] + sp[2][2] + sp[2][3];
    }
}

__global__ __launch_bounds__(256) void finalize_kernel(
    const float* __restrict__ part, float* __restrict__ out)
{
    // 3 sections x 2048 floats = 3 x 512 float4; 256 threads -> 6 float4 each
    const float4* p4 = reinterpret_cast<const float4*>(part);
    double a0 = 0.0, a1 = 0.0, a2 = 0.0;
    #pragma unroll
    for (int j = 0; j < 2; ++j) {
        float4 v0 = p4[0*512 + j*256 + threadIdx.x];
        float4 v1 = p4[1*512 + j*256 + threadIdx.x];
        float4 v2 = p4[2*512 + j*256 + threadIdx.x];
        a0 += (double)v0.x + (double)v0.y + (double)v0.z + (double)v0.w;
        a1 += (double)v1.x + (double)v1.y + (double)v1.z + (double)v1.w;
        a2 += (double)v2.x + (double)v2.y + (double)v2.z + (double)v2.w;
    }
    #pragma unroll
    for (int off = 32; off > 0; off >>= 1) {
        a0 += __shfl_down(a0, off, 64);
        a1 += __shfl_down(a1, off, 64);
        a2 += __shfl_down(a2, off, 64);
    }
    __shared__ double sp[3][4];
    const int lane = threadIdx.x & 63;
    const int wave = threadIdx.x >> 6;
    if (lane == 0) { sp[0][wave] = a0; sp[1][wave] = a1; sp[2][wave] = a2; }
    __syncthreads();
    if (threadIdx.x == 0) {
        double r = sp[0][0] + sp[0][1] + sp[0][2] + sp[0][3];
        double t = sp[1][0] + sp[1][1] + sp[1][2] + sp[1][3];
        double l = sp[2][0] + sp[2][1] + sp[2][2] + sp[2][3];
        out[0] = (float)(r / (4.0  * NROWS));
        out[1] = (float)(t / (3.0  * NROWS));
        out[2] = (float)(l / (64.0 * NROWS));
    }
}

extern "C" void kernel_launch(void* const* d_in, const int* in_sizes, int n_in,
                              void* d_out, int out_size, void* d_ws, size_t ws_size,
                              hipStream_t stream) {
    const float* pose_pred   = (const float*)d_in[0];
    const float* pose_gt     = (const float*)d_in[1];
    const float* trans_pred  = (const float*)d_in[2];
    const float* trans_gt    = (const float*)d_in[3];
    const float* latent_pred = (const float*)d_in[4];
    const float* latent_gt   = (const float*)d_in[5];
    float* out  = (float*)d_out;
    float* part = (float*)d_ws;

    hipLaunchKernelGGL(crit_fused_kernel, dim3(TOTAL_BLOCKS), dim3(BLOCK), 0, stream,
                       pose_pred, pose_gt, trans_pred, trans_gt,
                       latent_pred, latent_gt, out, part);
    hipLaunchKernelGGL(finalize_kernel, dim3(1), dim3(BLOCK), 0, stream, part, out);
}